// Round 9
// baseline (250.957 us; speedup 1.0000x reference)
//
#include <hip/hip_runtime.h>

#define NN 500
#define BB 32
#define TT 12
#define EMB 10

typedef float f2v __attribute__((ext_vector_type(2)));

// ---------------- K1: S = softmax(relu(E E^T) with diag=stay), rows ----------------
__global__ __launch_bounds__(256) void k_softmaxS(const float* __restrict__ E,
                                                  const int* __restrict__ stay,
                                                  float* __restrict__ S) {
    const int i = blockIdx.x;
    const int tid = threadIdx.x;
    __shared__ float row[NN];
    __shared__ float red[256];
    float ei[EMB];
#pragma unroll
    for (int d = 0; d < EMB; ++d) ei[d] = E[i * EMB + d];
    const float stayf = (float)stay[0];

    float lmax = -1e30f;
    for (int j = tid; j < NN; j += 256) {
        float acc = 0.f;
#pragma unroll
        for (int d = 0; d < EMB; ++d) acc += ei[d] * E[j * EMB + d];
        float v = acc > 0.f ? acc : 0.f;
        if (j == i) v = stayf;
        row[j] = v;
        lmax = fmaxf(lmax, v);
    }
    red[tid] = lmax;
    __syncthreads();
    for (int s = 128; s > 0; s >>= 1) {
        if (tid < s) red[tid] = fmaxf(red[tid], red[tid + s]);
        __syncthreads();
    }
    const float rmax = red[0];
    __syncthreads();

    float lsum = 0.f;
    for (int j = tid; j < NN; j += 256) {
        float e = __expf(row[j] - rmax);
        row[j] = e;
        lsum += e;
    }
    red[tid] = lsum;
    __syncthreads();
    for (int s = 128; s > 0; s >>= 1) {
        if (tid < s) red[tid] += red[tid + s];
        __syncthreads();
    }
    const float inv = 1.0f / red[0];
    for (int j = tid; j < NN; j += 256) S[i * NN + j] = row[j] * inv;
}

// ---------------- K2/K3: y[b,n] = sum_m S[n,m] * xin[b,m] (wave per row) ----------------
__global__ __launch_bounds__(256) void k_matvecS(const float* __restrict__ S,
                                                 const float* __restrict__ xin,
                                                 float* __restrict__ yout) {
    const int b = blockIdx.y;
    const int w = threadIdx.x >> 6;
    const int lane = threadIdx.x & 63;
    const int n = blockIdx.x * 4 + w;
    const float* xb = xin + b * NN;
    const float* Sr = S + n * NN;
    float acc = 0.f;
    for (int m = lane; m < NN; m += 64) acc += Sr[m] * xb[m];
#pragma unroll
    for (int off = 32; off > 0; off >>= 1) acc += __shfl_down(acc, off, 64);
    if (lane == 0) yout[b * NN + n] = acc;
}

// ---------------- K4: per-node small weights from embeddings ----------------
__global__ __launch_bounds__(256) void k_smallpre(const float* __restrict__ E,
                                                  const float* __restrict__ wp,
                                                  const float* __restrict__ bp,
                                                  const float* __restrict__ wwsp,
                                                  const float* __restrict__ wwtp,
                                                  float* __restrict__ W,
                                                  float* __restrict__ biasN,
                                                  float* __restrict__ wws,
                                                  float* __restrict__ wwt) {
    const int n = blockIdx.x;
    const int tid = threadIdx.x;
    __shared__ float e[EMB];
    if (tid < EMB) e[tid] = E[n * EMB + tid];
    __syncthreads();
    if (tid < 144) {
        float acc = 0.f;
#pragma unroll
        for (int d = 0; d < EMB; ++d) acc += e[d] * wp[d * 144 + tid];
        W[n * 144 + tid] = acc;
    } else if (tid < 208) {
        const int o = tid - 144;
        float acc = 0.f;
#pragma unroll
        for (int d = 0; d < EMB; ++d) acc += e[d] * bp[d * 64 + o];
        biasN[n * 64 + o] = acc;
    } else if (tid < 216) {
        const int o = tid - 208;
        float acc = 0.f;
#pragma unroll
        for (int d = 0; d < EMB; ++d) acc += e[d] * wwsp[d * 8 + o];
        wws[n * 8 + o] = acc;
    } else if (tid < 224) {
        const int o = tid - 216;
        float acc = 0.f;
#pragma unroll
        for (int d = 0; d < EMB; ++d) acc += e[d] * wwtp[d * 8 + o];
        wwt[n * 8 + o] = acc;
    }
}

// ---------------- K5: M[b,n] = mean_f xws, wsum[b,n] = sum_t xw[b,t,n]*T[t] ----------------
__global__ __launch_bounds__(128) void k_Mwsum(const float* __restrict__ xwin,
                                               const float* __restrict__ S,
                                               const int* __restrict__ bidx,
                                               const int* __restrict__ jumpc,
                                               const float* __restrict__ Tp,
                                               float* __restrict__ M,
                                               float* __restrict__ wsum) {
    const int b = blockIdx.y;
    const int n0 = blockIdx.x * 125;
    const int tid = threadIdx.x;
    __shared__ float xsf[NN];
    __shared__ float Tl[TT];
    const int t0 = bidx[0], t1 = bidx[1], t2 = bidx[2];
    if (tid < TT) Tl[tid] = Tp[tid];
    const float* xb = xwin + (size_t)b * TT * NN;
    for (int m = tid; m < NN; m += 128)
        xsf[m] = xb[t0 * NN + m] + xb[t1 * NN + m] + xb[t2 * NN + m];
    __syncthreads();
    if (tid < 125) {
        const int n = n0 + tid;
        float ws_ = 0.f;
#pragma unroll
        for (int t = 0; t < TT; ++t) ws_ += xb[t * NN + n] * Tl[t];
        const float jc = (float)jumpc[0];
        const float jterm = jc * (2.f * xb[t0 * NN + n] + xb[t1 * NN + n]);
        float acc = 0.f;
        for (int m = 0; m < NN; ++m) acc += xsf[m] * S[m * NN + n];
        M[b * NN + n] = (acc + jterm) * (1.f / 3.f);
        wsum[b * NN + n] = ws_;
    }
}

// ---------------- K_wpack: reorder conv weights -> wpack[t][kh][pipe][c][kw] (scalar) ----------------
__global__ __launch_bounds__(256) void k_wpack(const float* __restrict__ wm,
                                               const float* __restrict__ wx,
                                               float* __restrict__ wpack) {
    const int i = blockIdx.x * 256 + threadIdx.x;
    if (i >= TT * 72) return;
    const int t = i / 72;
    int r = i - t * 72;
    const int kh = r / 24; r -= kh * 24;
    const int pipe = r / 12; r -= pipe * 12;
    const int c = r / 3;
    const int kw = r - c * 3;
    const float* src = pipe ? wx : wm;
    wpack[i] = src[((c * TT + t) * 3 + kh) * 3 + kw];
}

// ---------------- K6 helpers ----------------
struct RowF { float4 q0; float4 q1; f2v q2; };

__device__ __forceinline__ void load_rows(const float* rp0, const float* rp1, const float* rp2,
                                          int voffA, int voffB, int voffC, bool wrap, RowF F[3]) {
    const char* p0 = reinterpret_cast<const char*>(rp0);
    const char* p1 = reinterpret_cast<const char*>(rp1);
    const char* p2 = reinterpret_cast<const char*>(rp2);
    F[0].q0 = *reinterpret_cast<const float4*>(p0 + voffA);
    F[0].q1 = *reinterpret_cast<const float4*>(p0 + voffB);
    F[0].q2 = *reinterpret_cast<const f2v*>(p0 + voffC);
    F[1].q0 = *reinterpret_cast<const float4*>(p1 + voffA);
    F[1].q1 = *reinterpret_cast<const float4*>(p1 + voffB);
    F[1].q2 = *reinterpret_cast<const f2v*>(p1 + voffC);
    F[2].q0 = *reinterpret_cast<const float4*>(p2 + voffA);
    F[2].q1 = *reinterpret_cast<const float4*>(p2 + voffB);
    F[2].q2 = *reinterpret_cast<const f2v*>(p2 + voffC);
    // in-place edge patch: keeps register pairs natural (cndmask on loaded regs)
    if (wrap) {
#pragma unroll
        for (int k = 0; k < 3; ++k) { F[k].q1.x = 0.f; F[k].q1.w = 0.f; }
    }
}

// one t: 3 kh x 3 kw x 8 ch x 4 col-pairs, pk-fma with pair-aligned windows
__device__ __forceinline__ void conv_body(const RowF F[3],
                                          const float* __restrict__ wb,
                                          f2v acc2[8][4]) {
#pragma unroll
    for (int kh = 0; kh < 3; ++kh) {
        // natural pairs P0..P4
        const f2v P0 = f2v{F[kh].q0.x, F[kh].q0.y};
        const f2v P1 = f2v{F[kh].q0.z, F[kh].q0.w};
        const f2v P2 = f2v{F[kh].q1.x, F[kh].q1.y};
        const f2v P3 = f2v{F[kh].q1.z, F[kh].q1.w};
        const f2v P4 = F[kh].q2;
        // cross pairs for kw=1
        const f2v M0 = f2v{P0.y, P1.x};
        const f2v M1 = f2v{P1.y, P2.x};
        const f2v M2 = f2v{P2.y, P3.x};
        const f2v M3 = f2v{P3.y, P4.x};
        const f2v winv[3][4] = {{P0, P1, P2, P3}, {M0, M1, M2, M3}, {P1, P2, P3, P4}};
        const float* wk = wb + kh * 24;
#pragma unroll
        for (int kw = 0; kw < 3; ++kw) {
#pragma unroll
            for (int c = 0; c < 8; ++c) {
                const float w = wk[((c & 4) ? 12 : 0) + (c & 3) * 3 + kw];
                const f2v ws = f2v{w, w};
#pragma unroll
                for (int p = 0; p < 4; ++p)
                    acc2[c][p] = __builtin_elementwise_fma(winv[kw][p], ws, acc2[c][p]);
            }
        }
    }
}

// ---------------- K6: fused dual conv — 4 rows/block, 8 cols/thread, pair-aligned pk fp32 ----------------
__global__ __launch_bounds__(256, 3) void k_conv(const float* __restrict__ MPG,
                                                 const float* __restrict__ wpack,
                                                 const float* __restrict__ bmv,
                                                 const float* __restrict__ bxv,
                                                 const float* __restrict__ zrow,
                                                 float* __restrict__ partials) {
    const int b = blockIdx.y;
    const int r0 = blockIdx.x * 4;
    const int tid = threadIdx.x;
    const int ry = __builtin_amdgcn_readfirstlane(tid >> 6);  // wave-uniform row 0..3
    const int tx = tid & 63;
    const bool active = (tx < 63);
    const bool wrap = (tx == 62);

    // wave-uniform (SGPR) row pointers
    const float* rp0;
    const float* rp1;
    const float* rp2;
    int adv0, adv1, adv2;
    {
        const float* base = MPG + (size_t)b * (TT * NN * NN);
        const int g0 = r0 + ry - 1, g2 = r0 + ry + 1;
        const bool ok0 = (g0 >= 0), ok2 = (g2 < NN);
        rp0 = ok0 ? base + (size_t)g0 * NN : zrow;
        rp1 = base + (size_t)(r0 + ry) * NN;
        rp2 = ok2 ? base + (size_t)g2 * NN : zrow;
        adv0 = ok0 ? NN * NN : 0;
        adv1 = NN * NN;
        adv2 = ok2 ? NN * NN : 0;
    }
    // thread covers output cols 8tx+1 .. 8tx+8 (wrap thread: 497..499 + col 0)
    const int voffA = active ? tx * 32 : 0;
    const int voffB = (active && !wrap) ? tx * 32 + 16 : 0;
    const int voffC = (active && !wrap) ? tx * 32 + 32 : 0;

    f2v acc2[8][4];
#pragma unroll
    for (int c = 0; c < 8; ++c) {
        const float bv = (c < 4) ? bmv[c] : bxv[c - 4];
#pragma unroll
        for (int p = 0; p < 4; ++p) acc2[c][p] = f2v{bv, bv};
    }

    RowF Fa[3], Fb[3];
    load_rows(rp0, rp1, rp2, voffA, voffB, voffC, wrap, Fa);
    rp0 += adv0; rp1 += adv1; rp2 += adv2;

#pragma unroll 1
    for (int t = 0; t < TT; t += 2) {
        load_rows(rp0, rp1, rp2, voffA, voffB, voffC, wrap, Fb);
        rp0 += adv0; rp1 += adv1; rp2 += adv2;
        conv_body(Fa, wpack + t * 72, acc2);
        if (t + 2 < TT) {
            load_rows(rp0, rp1, rp2, voffA, voffB, voffC, wrap, Fa);
            rp0 += adv0; rp1 += adv1; rp2 += adv2;
        }
        conv_body(Fb, wpack + (t + 1) * 72, acc2);
    }

    // per-slot validity masks (relu>=0 makes mask-by-zero safe for both sum and max)
    float mk[8];
#pragma unroll
    for (int v = 0; v < 8; ++v) {
        const bool ok = active && (!wrap || v < 3 || v == 7);
        mk[v] = ok ? 1.f : 0.f;
    }

    float vals[8];
#pragma unroll
    for (int c = 0; c < 4; ++c) {
        float s0 = 0.f, m0 = 0.f;
#pragma unroll
        for (int p = 0; p < 4; ++p) {
            const float a0 = fmaxf(acc2[c][p].x, 0.f) * mk[2 * p];
            const float a1 = fmaxf(acc2[c][p].y, 0.f) * mk[2 * p + 1];
            s0 += a0 + a1;
            const float b0 = fmaxf(acc2[c + 4][p].x, 0.f) * mk[2 * p];
            const float b1 = fmaxf(acc2[c + 4][p].y, 0.f) * mk[2 * p + 1];
            m0 = fmaxf(m0, fmaxf(b0, b1));
        }
        vals[c] = s0;
        vals[c + 4] = m0;
    }

    // wave butterfly reduce (one wave per output row)
#pragma unroll
    for (int off = 32; off > 0; off >>= 1) {
#pragma unroll
        for (int c = 0; c < 4; ++c) vals[c] += __shfl_xor(vals[c], off, 64);
#pragma unroll
        for (int c = 4; c < 8; ++c) vals[c] = fmaxf(vals[c], __shfl_xor(vals[c], off, 64));
    }
    __shared__ float wred[4][8];
    const int wv = tid >> 6;
    if (tx == 0) {
#pragma unroll
        for (int c = 0; c < 8; ++c) wred[wv][c] = vals[c];
    }
    __syncthreads();
    if (tid < 8) {
        const float a0 = wred[0][tid], a1 = wred[1][tid], a2 = wred[2][tid], a3 = wred[3][tid];
        const float r = (tid < 4) ? (a0 + a1 + a2 + a3) : fmaxf(fmaxf(a0, a1), fmaxf(a2, a3));
        partials[((size_t)b * 125 + blockIdx.x) * 8 + tid] = r;
    }
}

// ---------------- K7: reduce partials -> topo[b][8] ----------------
__global__ __launch_bounds__(256) void k_topo(const float* __restrict__ partials,
                                              float* __restrict__ topo) {
    const int b = blockIdx.x;
    const int tid = threadIdx.x;
    const int c = tid & 7;
    const int g = tid >> 3;  // 32 groups
    float vs = 0.f, vm = 0.f;
    for (int rp = g; rp < 125; rp += 32) {
        const float v = partials[((size_t)b * 125 + rp) * 8 + c];
        vs += v;
        vm = fmaxf(vm, v);
    }
    __shared__ float red[256];
    red[tid] = (c < 4) ? vs : vm;
    __syncthreads();
    for (int s = 16; s > 0; s >>= 1) {
        if (g < s) {
            const float a = red[tid];
            const float bv = red[tid + s * 8];
            red[tid] = (c < 4) ? (a + bv) : fmaxf(a, bv);
        }
        __syncthreads();
    }
    if (tid < 8) topo[b * 8 + tid] = (tid < 4) ? red[tid] * (1.f / (NN * (float)NN)) : red[tid];
}

// ---------------- K8: assemble output ----------------
__global__ __launch_bounds__(64) void k_out(const float* __restrict__ x,
                                            const float* __restrict__ y1,
                                            const float* __restrict__ y2,
                                            const float* __restrict__ W,
                                            const float* __restrict__ biasN,
                                            const float* __restrict__ wws,
                                            const float* __restrict__ wwt,
                                            const float* __restrict__ M,
                                            const float* __restrict__ wsum,
                                            const float* __restrict__ topo,
                                            float* __restrict__ out) {
    const int bn = blockIdx.x;
    const int b = bn / NN;
    const int n = bn - b * NN;
    const int o = threadIdx.x;
    float val;
    if (o < 48) {
        val = x[bn] * W[n * 144 + o] + y1[bn] * W[n * 144 + 48 + o] + y2[bn] * W[n * 144 + 96 + o];
    } else if (o < 56) {
        const int oo = o - 48;
        val = M[bn] * wws[n * 8 + oo] * topo[b * 8 + oo];
    } else {
        const int oo = o - 56;
        val = wsum[bn] * wwt[n * 8 + oo];
    }
    out[(size_t)bn * 64 + o] = val + biasN[n * 64 + o];
}

extern "C" void kernel_launch(void* const* d_in, const int* in_sizes, int n_in,
                              void* d_out, int out_size, void* d_ws, size_t ws_size,
                              hipStream_t stream) {
    const float* x    = (const float*)d_in[0];
    const float* xw   = (const float*)d_in[1];
    const float* E    = (const float*)d_in[2];
    const float* MPG  = (const float*)d_in[4];
    const int*   bidx = (const int*)d_in[5];
    const int*   stay = (const int*)d_in[7];
    const int*   jump = (const int*)d_in[8];
    const float* wp   = (const float*)d_in[9];
    const float* wwsp = (const float*)d_in[10];
    const float* wwtp = (const float*)d_in[11];
    const float* bp   = (const float*)d_in[12];
    const float* Tp   = (const float*)d_in[13];
    const float* cmw  = (const float*)d_in[14];
    const float* cmb  = (const float*)d_in[15];
    const float* cxw  = (const float*)d_in[16];
    const float* cxb  = (const float*)d_in[17];
    float* out = (float*)d_out;

    float* w = (float*)d_ws;
    float* S     = w;               // 250000
    float* y1    = S + 250000;      // 16000
    float* y2    = y1 + 16000;      // 16000
    float* W     = y2 + 16000;      // 72000
    float* biasN = W + 72000;       // 32000
    float* wws   = biasN + 32000;   // 4000
    float* wwt   = wws + 4000;      // 4000
    float* M     = wwt + 4000;      // 16000
    float* wsum  = M + 16000;       // 16000
    float* parts = wsum + 16000;    // 32000
    float* topo  = parts + 32000;   // 256
    float* zrow  = topo + 256;      // 640 floats zero page
    float* wpck  = zrow + 640;      // 864 packed weights + pad

    hipMemsetAsync(zrow, 0, 640 * sizeof(float), stream);
    k_wpack<<<4, 256, 0, stream>>>(cmw, cxw, wpck);
    k_softmaxS<<<NN, 256, 0, stream>>>(E, stay, S);
    k_matvecS<<<dim3(125, BB), 256, 0, stream>>>(S, x, y1);
    k_matvecS<<<dim3(125, BB), 256, 0, stream>>>(S, y1, y2);
    k_smallpre<<<NN, 256, 0, stream>>>(E, wp, bp, wwsp, wwtp, W, biasN, wws, wwt);
    k_Mwsum<<<dim3(4, BB), 128, 0, stream>>>(xw, S, bidx, jump, Tp, M, wsum);
    k_conv<<<dim3(125, BB), 256, 0, stream>>>(MPG, wpck, cmb, cxb, zrow, parts);
    k_topo<<<BB, 256, 0, stream>>>(parts, topo);
    k_out<<<BB * NN, 64, 0, stream>>>(x, y1, y2, W, biasN, wws, wwt, M, wsum, topo, out);
}

// Round 10
// 248.600 us; speedup vs baseline: 1.0095x; 1.0095x over previous
//
#include <hip/hip_runtime.h>

#define NN 500
#define BB 32
#define TT 12
#define EMB 10

typedef float f2v __attribute__((ext_vector_type(2)));
typedef float f4v __attribute__((ext_vector_type(4)));

#define PKFMA(A, W, C) asm("v_pk_fma_f32 %0, %1, %2, %0" : "+v"(A) : "v"(W), "v"(C))
#define SHUF2(V, a, b) __builtin_shufflevector((V), (V), (a), (b))

// ---------------- K1: S = softmax(relu(E E^T) with diag=stay), rows ----------------
__global__ __launch_bounds__(256) void k_softmaxS(const float* __restrict__ E,
                                                  const int* __restrict__ stay,
                                                  float* __restrict__ S) {
    const int i = blockIdx.x;
    const int tid = threadIdx.x;
    __shared__ float row[NN];
    __shared__ float red[256];
    float ei[EMB];
#pragma unroll
    for (int d = 0; d < EMB; ++d) ei[d] = E[i * EMB + d];
    const float stayf = (float)stay[0];

    float lmax = -1e30f;
    for (int j = tid; j < NN; j += 256) {
        float acc = 0.f;
#pragma unroll
        for (int d = 0; d < EMB; ++d) acc += ei[d] * E[j * EMB + d];
        float v = acc > 0.f ? acc : 0.f;
        if (j == i) v = stayf;
        row[j] = v;
        lmax = fmaxf(lmax, v);
    }
    red[tid] = lmax;
    __syncthreads();
    for (int s = 128; s > 0; s >>= 1) {
        if (tid < s) red[tid] = fmaxf(red[tid], red[tid + s]);
        __syncthreads();
    }
    const float rmax = red[0];
    __syncthreads();

    float lsum = 0.f;
    for (int j = tid; j < NN; j += 256) {
        float e = __expf(row[j] - rmax);
        row[j] = e;
        lsum += e;
    }
    red[tid] = lsum;
    __syncthreads();
    for (int s = 128; s > 0; s >>= 1) {
        if (tid < s) red[tid] += red[tid + s];
        __syncthreads();
    }
    const float inv = 1.0f / red[0];
    for (int j = tid; j < NN; j += 256) S[i * NN + j] = row[j] * inv;
}

// ---------------- K2/K3: y[b,n] = sum_m S[n,m] * xin[b,m] (wave per row) ----------------
__global__ __launch_bounds__(256) void k_matvecS(const float* __restrict__ S,
                                                 const float* __restrict__ xin,
                                                 float* __restrict__ yout) {
    const int b = blockIdx.y;
    const int w = threadIdx.x >> 6;
    const int lane = threadIdx.x & 63;
    const int n = blockIdx.x * 4 + w;
    const float* xb = xin + b * NN;
    const float* Sr = S + n * NN;
    float acc = 0.f;
    for (int m = lane; m < NN; m += 64) acc += Sr[m] * xb[m];
#pragma unroll
    for (int off = 32; off > 0; off >>= 1) acc += __shfl_down(acc, off, 64);
    if (lane == 0) yout[b * NN + n] = acc;
}

// ---------------- K4: per-node small weights from embeddings ----------------
__global__ __launch_bounds__(256) void k_smallpre(const float* __restrict__ E,
                                                  const float* __restrict__ wp,
                                                  const float* __restrict__ bp,
                                                  const float* __restrict__ wwsp,
                                                  const float* __restrict__ wwtp,
                                                  float* __restrict__ W,
                                                  float* __restrict__ biasN,
                                                  float* __restrict__ wws,
                                                  float* __restrict__ wwt) {
    const int n = blockIdx.x;
    const int tid = threadIdx.x;
    __shared__ float e[EMB];
    if (tid < EMB) e[tid] = E[n * EMB + tid];
    __syncthreads();
    if (tid < 144) {
        float acc = 0.f;
#pragma unroll
        for (int d = 0; d < EMB; ++d) acc += e[d] * wp[d * 144 + tid];
        W[n * 144 + tid] = acc;
    } else if (tid < 208) {
        const int o = tid - 144;
        float acc = 0.f;
#pragma unroll
        for (int d = 0; d < EMB; ++d) acc += e[d] * bp[d * 64 + o];
        biasN[n * 64 + o] = acc;
    } else if (tid < 216) {
        const int o = tid - 208;
        float acc = 0.f;
#pragma unroll
        for (int d = 0; d < EMB; ++d) acc += e[d] * wwsp[d * 8 + o];
        wws[n * 8 + o] = acc;
    } else if (tid < 224) {
        const int o = tid - 216;
        float acc = 0.f;
#pragma unroll
        for (int d = 0; d < EMB; ++d) acc += e[d] * wwtp[d * 8 + o];
        wwt[n * 8 + o] = acc;
    }
}

// ---------------- K5: M[b,n] = mean_f xws, wsum[b,n] = sum_t xw[b,t,n]*T[t] ----------------
__global__ __launch_bounds__(128) void k_Mwsum(const float* __restrict__ xwin,
                                               const float* __restrict__ S,
                                               const int* __restrict__ bidx,
                                               const int* __restrict__ jumpc,
                                               const float* __restrict__ Tp,
                                               float* __restrict__ M,
                                               float* __restrict__ wsum) {
    const int b = blockIdx.y;
    const int n0 = blockIdx.x * 125;
    const int tid = threadIdx.x;
    __shared__ float xsf[NN];
    __shared__ float Tl[TT];
    const int t0 = bidx[0], t1 = bidx[1], t2 = bidx[2];
    if (tid < TT) Tl[tid] = Tp[tid];
    const float* xb = xwin + (size_t)b * TT * NN;
    for (int m = tid; m < NN; m += 128)
        xsf[m] = xb[t0 * NN + m] + xb[t1 * NN + m] + xb[t2 * NN + m];
    __syncthreads();
    if (tid < 125) {
        const int n = n0 + tid;
        float ws_ = 0.f;
#pragma unroll
        for (int t = 0; t < TT; ++t) ws_ += xb[t * NN + n] * Tl[t];
        const float jc = (float)jumpc[0];
        const float jterm = jc * (2.f * xb[t0 * NN + n] + xb[t1 * NN + n]);
        float acc = 0.f;
        for (int m = 0; m < NN; ++m) acc += xsf[m] * S[m * NN + n];
        M[b * NN + n] = (acc + jterm) * (1.f / 3.f);
        wsum[b * NN + n] = ws_;
    }
}

// ---------------- K_wpack: duplicate-pair pack -> wpack2[t][kh][kw][c8][2] ----------------
__global__ __launch_bounds__(256) void k_wpack(const float* __restrict__ wm,
                                               const float* __restrict__ wx,
                                               float* __restrict__ wpack2) {
    const int i = blockIdx.x * 256 + threadIdx.x;
    if (i >= TT * 3 * 3 * 8 * 2) return;
    int j = i >> 1;
    const int c = j & 7; j >>= 3;
    const int kw = j % 3; j /= 3;
    const int kh = j % 3;
    const int t = j / 3;
    const float v = (c < 4) ? wm[((c * TT + t) * 3 + kh) * 3 + kw]
                            : wx[(((c - 4) * TT + t) * 3 + kh) * 3 + kw];
    wpack2[i] = v;
}

// ---------------- K6: fused dual conv — 2 rows/thread, pair-aligned v_pk_fma_f32 via asm ----------------
// Block: 256 threads = 2 row-pair groups x 128 col-threads. Block covers rows r0..r0+3, grid.x=125.
// Thread (g, tx): output rows R=r0+2g, R+1; cols 4tx..4tx+3 (tx<125 active).
// Stages rows R-1..R+2; windows per row: L={e-1,e0} P0={e0,e1} M={e1,e2} P1={e2,e3} R={e3,e4}.
struct RowD { f4v q; float eL, eR; };

__global__ __launch_bounds__(256, 3) void k_conv(const float* __restrict__ MPG,
                                                 const float* __restrict__ wpack2,
                                                 const float* __restrict__ bmv,
                                                 const float* __restrict__ bxv,
                                                 const float* __restrict__ zrow,
                                                 float* __restrict__ partials) {
    const int b = blockIdx.y;
    const int r0 = blockIdx.x * 4;
    const int tid = threadIdx.x;
    const int g = __builtin_amdgcn_readfirstlane(tid >> 7);  // wave-uniform row-pair
    const int tx = tid & 127;
    const bool active = (tx < 125);
    const int R = r0 + 2 * g;

    const float* rp[4];
    int adv[4];
    {
        const float* base = MPG + (size_t)b * (TT * NN * NN);
#pragma unroll
        for (int k = 0; k < 4; ++k) {
            const int gr = R - 1 + k;
            const bool ok = (gr >= 0) && (gr < NN);
            rp[k] = ok ? base + (size_t)gr * NN : zrow;
            adv[k] = ok ? NN * NN : 0;
        }
    }
    const int voffQ = active ? tx * 16 : 0;
    const int voffL = (active && tx > 0) ? tx * 16 - 4 : 0;
    const int voffR = (active && tx < 124) ? tx * 16 + 16 : 0;
    const float mL = (active && tx > 0) ? 1.f : 0.f;
    const float mR = (active && tx < 124) ? 1.f : 0.f;

    f2v accA[8][2], accB[8][2];
#pragma unroll
    for (int c = 0; c < 8; ++c) {
        const float bv = (c < 4) ? bmv[c] : bxv[c - 4];
#pragma unroll
        for (int p = 0; p < 2; ++p) {
            accA[c][p] = f2v{bv, bv};
            accB[c][p] = f2v{bv, bv};
        }
    }

    RowD Da[4], Db[4];

    auto LOAD = [&](RowD D[4]) {
#pragma unroll
        for (int k = 0; k < 4; ++k) {
            const char* p = reinterpret_cast<const char*>(rp[k]);
            D[k].q = *reinterpret_cast<const f4v*>(p + voffQ);
            D[k].eL = *reinterpret_cast<const float*>(p + voffL);
            D[k].eR = *reinterpret_cast<const float*>(p + voffR);
        }
#pragma unroll
        for (int k = 0; k < 4; ++k) rp[k] += adv[k];
    };

    auto BODY = [&](RowD D[4], const float* wb) {
        f2v P0[4], P1[4], Lw[4], Mw[4], Rw[4];
#pragma unroll
        for (int k = 0; k < 4; ++k) {
            const f4v q = D[k].q;
            P0[k] = SHUF2(q, 0, 1);
            P1[k] = SHUF2(q, 2, 3);
            Mw[k] = SHUF2(q, 1, 2);
            Lw[k] = f2v{D[k].eL * mL, q.x};
            Rw[k] = f2v{q.w, D[k].eR * mR};
        }
#pragma unroll
        for (int kh = 0; kh < 3; ++kh) {
            const int ka = kh, kb = kh + 1;
            const float* wk = wb + kh * 48;
#pragma unroll
            for (int kw = 0; kw < 3; ++kw) {
                const f4v w01 = *reinterpret_cast<const f4v*>(wk + kw * 16);
                const f4v w23 = *reinterpret_cast<const f4v*>(wk + kw * 16 + 4);
                const f4v w45 = *reinterpret_cast<const f4v*>(wk + kw * 16 + 8);
                const f4v w67 = *reinterpret_cast<const f4v*>(wk + kw * 16 + 12);
                const f2v wc[8] = {SHUF2(w01, 0, 1), SHUF2(w01, 2, 3),
                                   SHUF2(w23, 0, 1), SHUF2(w23, 2, 3),
                                   SHUF2(w45, 0, 1), SHUF2(w45, 2, 3),
                                   SHUF2(w67, 0, 1), SHUF2(w67, 2, 3)};
                const f2v A0 = (kw == 0) ? Lw[ka] : ((kw == 1) ? P0[ka] : Mw[ka]);
                const f2v A1 = (kw == 0) ? Mw[ka] : ((kw == 1) ? P1[ka] : Rw[ka]);
                const f2v B0 = (kw == 0) ? Lw[kb] : ((kw == 1) ? P0[kb] : Mw[kb]);
                const f2v B1 = (kw == 0) ? Mw[kb] : ((kw == 1) ? P1[kb] : Rw[kb]);
#pragma unroll
                for (int c = 0; c < 8; ++c) {
                    PKFMA(accA[c][0], A0, wc[c]);
                    PKFMA(accA[c][1], A1, wc[c]);
                    PKFMA(accB[c][0], B0, wc[c]);
                    PKFMA(accB[c][1], B1, wc[c]);
                }
            }
        }
    };

    LOAD(Da);
#pragma unroll 1
    for (int t = 0; t < TT; t += 2) {
        LOAD(Db);
        BODY(Da, wpack2 + t * 144);
        if (t + 2 < TT) LOAD(Da);
        BODY(Db, wpack2 + (t + 1) * 144);
    }

    // relu + per-thread reduce over 2 rows x 4 cols
    const float mk = active ? 1.f : 0.f;
    float vals[8];
#pragma unroll
    for (int c = 0; c < 4; ++c) {
        float s0 = 0.f, m0 = 0.f;
#pragma unroll
        for (int p = 0; p < 2; ++p) {
            s0 += fmaxf(accA[c][p].x, 0.f) + fmaxf(accA[c][p].y, 0.f)
                + fmaxf(accB[c][p].x, 0.f) + fmaxf(accB[c][p].y, 0.f);
            m0 = fmaxf(m0, fmaxf(fmaxf(accA[c + 4][p].x, 0.f), fmaxf(accA[c + 4][p].y, 0.f)));
            m0 = fmaxf(m0, fmaxf(fmaxf(accB[c + 4][p].x, 0.f), fmaxf(accB[c + 4][p].y, 0.f)));
        }
        vals[c] = s0 * mk;
        vals[c + 4] = m0 * mk;
    }

    // wave butterfly reduce
#pragma unroll
    for (int off = 32; off > 0; off >>= 1) {
#pragma unroll
        for (int c = 0; c < 4; ++c) vals[c] += __shfl_xor(vals[c], off, 64);
#pragma unroll
        for (int c = 4; c < 8; ++c) vals[c] = fmaxf(vals[c], __shfl_xor(vals[c], off, 64));
    }
    __shared__ float wred[4][8];
    const int wv = tid >> 6;
    const int lane = tid & 63;
    if (lane == 0) {
#pragma unroll
        for (int c = 0; c < 8; ++c) wred[wv][c] = vals[c];
    }
    __syncthreads();
    if (tid < 8) {
        const float a0 = wred[0][tid], a1 = wred[1][tid], a2 = wred[2][tid], a3 = wred[3][tid];
        const float r = (tid < 4) ? (a0 + a1 + a2 + a3) : fmaxf(fmaxf(a0, a1), fmaxf(a2, a3));
        partials[((size_t)b * 125 + blockIdx.x) * 8 + tid] = r;
    }
}

// ---------------- K7: reduce partials -> topo[b][8] ----------------
__global__ __launch_bounds__(256) void k_topo(const float* __restrict__ partials,
                                              float* __restrict__ topo) {
    const int b = blockIdx.x;
    const int tid = threadIdx.x;
    const int c = tid & 7;
    const int g = tid >> 3;  // 32 groups
    float vs = 0.f, vm = 0.f;
    for (int rp = g; rp < 125; rp += 32) {
        const float v = partials[((size_t)b * 125 + rp) * 8 + c];
        vs += v;
        vm = fmaxf(vm, v);
    }
    __shared__ float red[256];
    red[tid] = (c < 4) ? vs : vm;
    __syncthreads();
    for (int s = 16; s > 0; s >>= 1) {
        if (g < s) {
            const float a = red[tid];
            const float bv = red[tid + s * 8];
            red[tid] = (c < 4) ? (a + bv) : fmaxf(a, bv);
        }
        __syncthreads();
    }
    if (tid < 8) topo[b * 8 + tid] = (tid < 4) ? red[tid] * (1.f / (NN * (float)NN)) : red[tid];
}

// ---------------- K8: assemble output ----------------
__global__ __launch_bounds__(64) void k_out(const float* __restrict__ x,
                                            const float* __restrict__ y1,
                                            const float* __restrict__ y2,
                                            const float* __restrict__ W,
                                            const float* __restrict__ biasN,
                                            const float* __restrict__ wws,
                                            const float* __restrict__ wwt,
                                            const float* __restrict__ M,
                                            const float* __restrict__ wsum,
                                            const float* __restrict__ topo,
                                            float* __restrict__ out) {
    const int bn = blockIdx.x;
    const int b = bn / NN;
    const int n = bn - b * NN;
    const int o = threadIdx.x;
    float val;
    if (o < 48) {
        val = x[bn] * W[n * 144 + o] + y1[bn] * W[n * 144 + 48 + o] + y2[bn] * W[n * 144 + 96 + o];
    } else if (o < 56) {
        const int oo = o - 48;
        val = M[bn] * wws[n * 8 + oo] * topo[b * 8 + oo];
    } else {
        const int oo = o - 56;
        val = wsum[bn] * wwt[n * 8 + oo];
    }
    out[(size_t)bn * 64 + o] = val + biasN[n * 64 + o];
}

extern "C" void kernel_launch(void* const* d_in, const int* in_sizes, int n_in,
                              void* d_out, int out_size, void* d_ws, size_t ws_size,
                              hipStream_t stream) {
    const float* x    = (const float*)d_in[0];
    const float* xw   = (const float*)d_in[1];
    const float* E    = (const float*)d_in[2];
    const float* MPG  = (const float*)d_in[4];
    const int*   bidx = (const int*)d_in[5];
    const int*   stay = (const int*)d_in[7];
    const int*   jump = (const int*)d_in[8];
    const float* wp   = (const float*)d_in[9];
    const float* wwsp = (const float*)d_in[10];
    const float* wwtp = (const float*)d_in[11];
    const float* bp   = (const float*)d_in[12];
    const float* Tp   = (const float*)d_in[13];
    const float* cmw  = (const float*)d_in[14];
    const float* cmb  = (const float*)d_in[15];
    const float* cxw  = (const float*)d_in[16];
    const float* cxb  = (const float*)d_in[17];
    float* out = (float*)d_out;

    float* w = (float*)d_ws;
    float* S     = w;               // 250000
    float* y1    = S + 250000;      // 16000
    float* y2    = y1 + 16000;      // 16000
    float* W     = y2 + 16000;      // 72000
    float* biasN = W + 72000;       // 32000
    float* wws   = biasN + 32000;   // 4000
    float* wwt   = wws + 4000;      // 4000
    float* M     = wwt + 4000;      // 16000
    float* wsum  = M + 16000;       // 16000
    float* parts = wsum + 16000;    // 32000
    float* topo  = parts + 32000;   // 256
    float* zrow  = topo + 256;      // 640 floats zero page
    float* wpck  = zrow + 640;      // 1728 duplicated weight pairs

    hipMemsetAsync(zrow, 0, 640 * sizeof(float), stream);
    k_wpack<<<7, 256, 0, stream>>>(cmw, cxw, wpck);
    k_softmaxS<<<NN, 256, 0, stream>>>(E, stay, S);
    k_matvecS<<<dim3(125, BB), 256, 0, stream>>>(S, x, y1);
    k_matvecS<<<dim3(125, BB), 256, 0, stream>>>(S, y1, y2);
    k_smallpre<<<NN, 256, 0, stream>>>(E, wp, bp, wwsp, wwtp, W, biasN, wws, wwt);
    k_Mwsum<<<dim3(4, BB), 128, 0, stream>>>(xw, S, bidx, jump, Tp, M, wsum);
    k_conv<<<dim3(125, BB), 256, 0, stream>>>(MPG, wpck, cmb, cxb, zrow, parts);
    k_topo<<<BB, 256, 0, stream>>>(parts, topo);
    k_out<<<BB * NN, 64, 0, stream>>>(x, y1, y2, W, biasN, wws, wwt, M, wsum, topo, out);
}